// Round 4
// baseline (83.321 us; speedup 1.0000x reference)
//
#include <hip/hip_runtime.h>

// One-sided Chamfer: for each x_i (N=16384), min_j ||y_j - x_i||^2 over M=16384 y.
// t_ij = ||y_j||^2 - 2 x_i.y_j  (per-y precomputed as float4(-2y0,-2y1,-2y2,||y||^2))
// dist2_i = ||x_i||^2 + min_j t_ij
//
// R4 (single-variable change vs R3, 82.35us): packed-fp32 inner loop.
// gfx950 VOP3P has v_pk_fma_f32 (2x f32 FMA per instruction). Pair x-points into
// float2 ext-vectors + __builtin_elementwise_fma so LLVM forms pk_fma:
// per 2y x 2x = 4 pairs: 6 pk_fma + 2 min => ~2.0 issue-slots/pair vs 3.5 scalar.
// Structure (atomicMin merge, init/main/sum dispatches, S=128, LDS broadcast)
// unchanged from R3.

typedef float v2f __attribute__((ext_vector_type(2)));

constexpr int TPB = 256;         // threads per block
constexpr int XPT = 8;           // x points per thread (4 float2 pairs)
constexpr int MAX_YCHUNK = 512;  // LDS: 512 * 16B = 8KB

__global__ __launch_bounds__(TPB) void chamfer_init(float* __restrict__ out, int N) {
  const int i = blockIdx.x * TPB + threadIdx.x;
  if (i == 0) out[0] = 0.0f;
  if (i < N) out[1 + i] = __builtin_inff();
}

__global__ __launch_bounds__(TPB) void chamfer_main(
    const float* __restrict__ x, const float* __restrict__ y,
    float* __restrict__ out, int N, int M, int ychunk) {
  __shared__ float4 sy[MAX_YCHUNK];
  const int t = threadIdx.x;
  const int bx = blockIdx.x;       // x block (TPB*XPT x-points)
  const int s = blockIdx.y;        // y chunk index

  // Stage + transform this block's y chunk into LDS (pad to even count).
  const int ycap = (ychunk + 1) & ~1;
  for (int jj = t; jj < ycap; jj += TPB) {
    const int j = s * ychunk + jj;
    if (jj < ychunk && j < M) {
      const float y0 = y[3 * j], y1 = y[3 * j + 1], y2 = y[3 * j + 2];
      sy[jj] = make_float4(-2.0f * y0, -2.0f * y1, -2.0f * y2,
                           fmaf(y0, y0, fmaf(y1, y1, y2 * y2)));
    } else {
      sy[jj] = make_float4(0.0f, 0.0f, 0.0f, __builtin_inff());
    }
  }
  __syncthreads();

  // 8 x-points as 4 float2 lanes-pairs: halves are x-points (2p)*TPB+t and
  // (2p+1)*TPB+t.
  v2f X0[XPT / 2], X1[XPT / 2], X2[XPT / 2], mn2[XPT / 2];
#pragma unroll
  for (int p = 0; p < XPT / 2; p++) {
    const int ia = bx * (TPB * XPT) + (2 * p) * TPB + t;
    const int ib = bx * (TPB * XPT) + (2 * p + 1) * TPB + t;
    const int ca = (ia < N) ? ia : 0;
    const int cb = (ib < N) ? ib : 0;
    X0[p].x = x[3 * ca];     X0[p].y = x[3 * cb];
    X1[p].x = x[3 * ca + 1]; X1[p].y = x[3 * cb + 1];
    X2[p].x = x[3 * ca + 2]; X2[p].y = x[3 * cb + 2];
    mn2[p] = __builtin_inff();
  }

  // 2 y-points per iteration. Wave-uniform LDS address -> broadcast,
  // conflict-free. Per p per iter: 6 v_pk_fma_f32 + 2 packed/scalar mins.
#pragma unroll 4
  for (int jj = 0; jj < ycap; jj += 2) {
    const float4 qa = sy[jj];
    const float4 qb = sy[jj + 1];
    const v2f qax = qa.x, qay = qa.y, qaz = qa.z, qaw = qa.w;
    const v2f qbx = qb.x, qby = qb.y, qbz = qb.z, qbw = qb.w;
#pragma unroll
    for (int p = 0; p < XPT / 2; p++) {
      const v2f ta = __builtin_elementwise_fma(
          X0[p], qax,
          __builtin_elementwise_fma(X1[p], qay,
                                    __builtin_elementwise_fma(X2[p], qaz, qaw)));
      const v2f tb = __builtin_elementwise_fma(
          X0[p], qbx,
          __builtin_elementwise_fma(X1[p], qby,
                                    __builtin_elementwise_fma(X2[p], qbz, qbw)));
      mn2[p] = __builtin_elementwise_min(mn2[p],
                                         __builtin_elementwise_min(ta, tb));
    }
  }

  // d = ||x||^2 + min_chunk t  >= 0, so uint compare == float compare.
  unsigned int* uo = (unsigned int*)(out + 1);
#pragma unroll
  for (int p = 0; p < XPT / 2; p++) {
    const int ia = bx * (TPB * XPT) + (2 * p) * TPB + t;
    const int ib = bx * (TPB * XPT) + (2 * p + 1) * TPB + t;
    if (ia < N) {
      const float d =
          fmaf(X0[p].x, X0[p].x, fmaf(X1[p].x, X1[p].x, X2[p].x * X2[p].x)) +
          mn2[p].x;
      atomicMin(&uo[ia], __float_as_uint(d));
    }
    if (ib < N) {
      const float d =
          fmaf(X0[p].y, X0[p].y, fmaf(X1[p].y, X1[p].y, X2[p].y * X2[p].y)) +
          mn2[p].y;
      atomicMin(&uo[ib], __float_as_uint(d));
    }
  }
}

__global__ __launch_bounds__(TPB) void chamfer_sum(
    float* __restrict__ out, int N) {
  const int t = threadIdx.x;
  const int i = blockIdx.x * TPB + t;

  float v = (i < N) ? out[1 + i] : 0.0f;
#pragma unroll
  for (int off = 32; off > 0; off >>= 1) v += __shfl_down(v, off, 64);
  __shared__ float wsum[TPB / 64];
  if ((t & 63) == 0) wsum[t >> 6] = v;
  __syncthreads();
  if (t == 0) {
    float ssum = 0.0f;
#pragma unroll
    for (int w = 0; w < TPB / 64; w++) ssum += wsum[w];
    atomicAdd(out, ssum);
  }
}

extern "C" void kernel_launch(void* const* d_in, const int* in_sizes, int n_in,
                              void* d_out, int out_size, void* d_ws, size_t ws_size,
                              hipStream_t stream) {
  const float* x = (const float*)d_in[0];
  const float* y = (const float*)d_in[1];
  float* out = (float*)d_out;

  const int N = in_sizes[0] / 3;  // 16384
  const int M = in_sizes[1] / 3;  // 16384

  // S=128 -> ychunk=128, grid 8x128=1024 blocks (4/CU, 16 waves/CU).
  int S = 128;
  int ychunk = (M + S - 1) / S;
  while (ychunk > MAX_YCHUNK) { S <<= 1; ychunk = (M + S - 1) / S; }

  const int iblocks = (N + TPB - 1) / TPB;  // 64
  chamfer_init<<<iblocks, TPB, 0, stream>>>(out, N);

  const int xblocks = (N + TPB * XPT - 1) / (TPB * XPT);  // 8
  dim3 gridB(xblocks, S);                                  // 1024 blocks
  chamfer_main<<<gridB, TPB, 0, stream>>>(x, y, out, N, M, ychunk);

  chamfer_sum<<<iblocks, TPB, 0, stream>>>(out, N);
}